// Round 15
// baseline (98.165 us; speedup 1.0000x reference)
//
#include <hip/hip_runtime.h>
#include <math.h>

#define BB 1024        // batch
#define DD 512         // feature dim
#define CC 50000       // classes
#define KMAX 1024      // column space = batch rows (first-occurrence active)
#define HSZ 2048       // class->first-column hash size
#define PLCAP 32       // per-row positive-list capacity (expected ~2-6)
#define OVCAP 64       // overflow (lmem-valid unseen) class capacity
#define OVROW 8        // per-row overflow positive capacity
#define SCALE_F 16.0f
#define EPS_F 0.1f

typedef __bf16 bf16_t;
typedef bf16_t bf16x2 __attribute__((ext_vector_type(2)));
typedef bf16_t bf16x8 __attribute__((ext_vector_type(8)));
typedef float f32x4 __attribute__((ext_vector_type(4)));

__device__ __forceinline__ unsigned hashc(int c) {
    return ((unsigned)c * 2654435761u) >> 21;   // 0..2047
}

// =======================================================================
// D1: setup — row splits + rt, column (first-occurrence) class splits +
//     class->first-column hash insert, lmem overflow scan.
// =======================================================================
__global__ __launch_bounds__(256, 4) void k_setup(
        const float* __restrict__ inputs, const float* __restrict__ fmem,
        const int* __restrict__ targets, const int* __restrict__ lmem,
        bf16_t* __restrict__ AH, bf16_t* __restrict__ AL,
        bf16_t* __restrict__ BH, bf16_t* __restrict__ BL,
        float* __restrict__ rnA, float* __restrict__ rnB,
        int* __restrict__ rt, int* __restrict__ afirst,
        int* __restrict__ gkey, int* __restrict__ gval,
        int* __restrict__ ovc, int* __restrict__ ovcnt)
{
    __shared__ int tl[BB];
    __shared__ int members[BB];
    __shared__ float red[256];
    __shared__ int mc;
    const int bid = blockIdx.x, tid = threadIdx.x;

    for (int i = tid; i < BB; i += 256) tl[i] = targets[i];
    __syncthreads();

    if (bid < BB) {
        // ---- row path: rt[b] (first index of own target) + split + rnA ----
        int b = bid, tgt = tl[b];
        int lmin = 0x7fffffff;
        for (int j = tid; j < BB; j += 256)
            if (tl[j] == tgt && j < lmin) lmin = j;
        members[tid] = lmin;
        __syncthreads();
        for (int s = 128; s > 0; s >>= 1) {
            if (tid < s) members[tid] = min(members[tid], members[tid + s]);
            __syncthreads();
        }
        if (tid == 0) rt[b] = members[0];
        int d0 = tid * 2;
        float a0 = inputs[b * DD + d0];
        float a1 = inputs[b * DD + d0 + 1];
        red[tid] = a0 * a0 + a1 * a1;
        __syncthreads();
        for (int s = 128; s > 0; s >>= 1) {
            if (tid < s) red[tid] += red[tid + s];
            __syncthreads();
        }
        if (tid == 0) rnA[b] = 1.0f / fmaxf(sqrtf(red[0]), 1e-12f);
        bf16_t h0 = (bf16_t)a0, h1 = (bf16_t)a1;
        bf16x2 ph; ph[0] = h0; ph[1] = h1;
        bf16x2 pl; pl[0] = (bf16_t)(a0 - (float)h0); pl[1] = (bf16_t)(a1 - (float)h1);
        *(bf16x2*)(AH + b * DD + d0) = ph;
        *(bf16x2*)(AL + b * DD + d0) = pl;
    } else if (bid < 2 * BB) {
        // ---- column path: first-occurrence? class-mean split + rnB + hash --
        int j = bid - BB, tgt = tl[j];
        if (tid == 0) mc = 0;
        __syncthreads();
        int lmin = 0x7fffffff;
        for (int i = tid; i < BB; i += 256)
            if (tl[i] == tgt) { int s = atomicAdd(&mc, 1); members[s] = i; if (i < lmin) lmin = i; }
        red[tid] = (float)lmin;
        __syncthreads();
        for (int s = 128; s > 0; s >>= 1) {
            if (tid < s) red[tid] = fminf(red[tid], red[tid + s]);
            __syncthreads();
        }
        bool first = ((int)red[0] == j);
        int d0 = tid * 2;
        if (!first) {                       // duplicate class: dead column
            bf16x2 z; z[0] = (bf16_t)0.0f; z[1] = (bf16_t)0.0f;
            *(bf16x2*)(BH + j * DD + d0) = z;
            *(bf16x2*)(BL + j * DD + d0) = z;
            if (tid == 0) { rnB[j] = 0.0f; afirst[j] = 0; }
            return;
        }
        if (tid == 0) {                     // insert (class -> first column)
            unsigned h = hashc(tgt);
            while (true) {
                int old = atomicCAS(&gkey[h], 0, tgt + 1);
                if (old == 0) { gval[h] = j; break; }
                if (old == tgt + 1) break;  // impossible (unique first)
                h = (h + 1) & (HSZ - 1);
            }
        }
        int m = mc;
        float b0v = 0.0f, b1v = 0.0f;       // sum members; /count cancels
        for (int i = 0; i < m; ++i) {
            int bb = members[i];
            b0v += inputs[bb * DD + d0];
            b1v += inputs[bb * DD + d0 + 1];
        }
        __syncthreads();
        red[tid] = b0v * b0v + b1v * b1v;
        __syncthreads();
        for (int s = 128; s > 0; s >>= 1) {
            if (tid < s) red[tid] += red[tid + s];
            __syncthreads();
        }
        if (tid == 0) { rnB[j] = 1.0f / fmaxf(sqrtf(red[0]), 1e-12f); afirst[j] = 1; }
        bf16_t g0 = (bf16_t)b0v, g1 = (bf16_t)b1v;
        bf16x2 ph; ph[0] = g0; ph[1] = g1;
        bf16x2 pl; pl[0] = (bf16_t)(b0v - (float)g0); pl[1] = (bf16_t)(b1v - (float)g1);
        *(bf16x2*)(BH + j * DD + d0) = ph;
        *(bf16x2*)(BL + j * DD + d0) = pl;
    } else {
        // ---- lmem overflow scan (lmem is all -1 in this workload) ----
        int c = (bid - 2 * BB) * 256 + tid;
        if (c < CC && lmem[c] != -1) {
            bool seen = false;
            for (int i = 0; i < BB; ++i) if (tl[i] == c) { seen = true; break; }
            if (!seen) { int s = atomicAdd(ovcnt, 1); if (s < OVCAP) ovc[s] = c; }
        }
    }
}

// =======================================================================
// D2: coalesced pm stream-scan (2048 blocks, the HBM long pole) ∥
//     1024 MFMA tiles ∥ overflow blocks.
// =======================================================================
__global__ __launch_bounds__(256, 8) void k_main(
        const float* __restrict__ pm, const int* __restrict__ targets,
        const int* __restrict__ afirst,
        const int* __restrict__ gkey, const int* __restrict__ gval,
        const bf16_t* __restrict__ AH, const bf16_t* __restrict__ AL,
        const bf16_t* __restrict__ BH, const bf16_t* __restrict__ BL,
        const float* __restrict__ rnA, const float* __restrict__ rnB,
        float* __restrict__ simc, float* __restrict__ seP,
        int* __restrict__ pcnt, int* __restrict__ pkidx, float* __restrict__ pval,
        const float* __restrict__ inputs, const float* __restrict__ fmem,
        const int* __restrict__ ovc, const int* __restrict__ ovcnt,
        int* __restrict__ ovrCnt, float* __restrict__ ovS, float* __restrict__ ovV,
        float* __restrict__ ovSe)
{
    __shared__ float red[256];
    const int bid = blockIdx.x, tid = threadIdx.x;

    if (bid < 2 * BB) {
        // ---- stream-scan: half a pm row, coalesced float4; hash at nonzeros
        int b = bid >> 1, half = bid & 1;
        const int HQ = CC / 8;              // 6250 float4 per half-row
        const f32x4* __restrict__ rowv = (const f32x4*)(pm + (size_t)b * CC) + half * HQ;
        int cbase = half * (CC / 2);
        for (int i = tid; i < HQ; i += 256) {
            f32x4 v = rowv[i];
            if (v[0] != 0.0f || v[1] != 0.0f || v[2] != 0.0f || v[3] != 0.0f) {
                #pragma unroll
                for (int j = 0; j < 4; ++j) {
                    if (v[j] != 0.0f) {
                        int c = cbase + i * 4 + j;
                        unsigned h = hashc(c);
                        while (true) {
                            int k = gkey[h];            // L2-hot 8KB table
                            if (k == c + 1) {
                                int col = gval[h];      // first-occurrence column
                                int s = atomicAdd(&pcnt[b], 1);
                                if (s < PLCAP) {
                                    pkidx[b * PLCAP + s] = col;
                                    pval[b * PLCAP + s] = v[j];
                                }
                                break;
                            }
                            if (k == 0) break;          // not a target class
                            h = (h + 1) & (HSZ - 1);
                        }
                    }
                }
            }
        }
    } else if (bid < 3 * BB) {
        // ---- GEMM tile: 4 waves x one 16x16 quadrant, bf16 3-term split ----
        int t = bid - 2 * BB;
        float* sem = red;                  // 32 per-row exp partials
        if (tid < 32) sem[tid] = 0.0f;
        __syncthreads();
        int wave = tid >> 6, lane = tid & 63;
        int by = t >> 5, bx = t & 31;
        int b0 = by * 32 + (wave >> 1) * 16;
        int k0 = bx * 32 + (wave & 1) * 16;
        int frow = lane & 15;
        int koff = (lane >> 4) * 8;
        const bf16_t* pAh = AH + (size_t)(b0 + frow) * DD + koff;
        const bf16_t* pAl = AL + (size_t)(b0 + frow) * DD + koff;
        const bf16_t* pBh = BH + (size_t)(k0 + frow) * DD + koff;
        const bf16_t* pBl = BL + (size_t)(k0 + frow) * DD + koff;
        f32x4 acc = {};
        #pragma unroll 2
        for (int dk = 0; dk < DD; dk += 32) {
            bf16x8 ah = *(const bf16x8*)(pAh + dk);
            bf16x8 al = *(const bf16x8*)(pAl + dk);
            bf16x8 bh = *(const bf16x8*)(pBh + dk);
            bf16x8 bl = *(const bf16x8*)(pBl + dk);
            acc = __builtin_amdgcn_mfma_f32_16x16x32_bf16(ah, bh, acc, 0, 0, 0);
            acc = __builtin_amdgcn_mfma_f32_16x16x32_bf16(ah, bl, acc, 0, 0, 0);
            acc = __builtin_amdgcn_mfma_f32_16x16x32_bf16(al, bh, acc, 0, 0, 0);
        }
        // C/D layout: col = lane&15, row = (lane>>4)*4 + reg
        int r4 = (lane >> 4) * 4;
        int col = k0 + (lane & 15);
        float rb = rnB[col];
        int act = afirst[col];
        #pragma unroll
        for (int r = 0; r < 4; ++r) {
            int row = b0 + r4 + r;
            float s = acc[r] * SCALE_F * rnA[row] * rb;
            simc[(size_t)row * KMAX + col] = s;
            float e = act ? expf(s) : 0.0f;
            #pragma unroll
            for (int o = 1; o < 16; o <<= 1) e += __shfl_xor(e, o, 16);
            if ((lane & 15) == 0) atomicAdd(&sem[(wave >> 1) * 16 + r4 + r], e);
        }
        __syncthreads();
        if (tid < 32) seP[(size_t)(by * 32 + tid) * 32 + bx] = sem[tid];  // plain store
    } else {
        // ---- overflow classes (lmem-valid, unseen): generality path ----
        int i = bid - 3 * BB;
        int n = *ovcnt; if (n > OVCAP) n = OVCAP;
        if (i >= n) return;
        int c = ovc[i];
        float nn = 0.0f;
        for (int d = tid; d < DD; d += 256) { float x = fmem[(size_t)c * DD + d]; nn += x * x; }
        red[tid] = nn;
        __syncthreads();
        for (int s = 128; s > 0; s >>= 1) {
            if (tid < s) red[tid] += red[tid + s];
            __syncthreads();
        }
        float rn = 1.0f / fmaxf(sqrtf(red[0]), 1e-12f);
        __syncthreads();
        for (int b = 0; b < BB; ++b) {
            float part = 0.0f;
            for (int d = tid; d < DD; d += 256)
                part += inputs[b * DD + d] * fmem[(size_t)c * DD + d];
            red[tid] = part;
            __syncthreads();
            for (int s = 128; s > 0; s >>= 1) {
                if (tid < s) red[tid] += red[tid + s];
                __syncthreads();
            }
            if (tid == 0) {
                float s = SCALE_F * rnA[b] * rn * red[0];
                atomicAdd(&ovSe[b], expf(s));
                float v = pm[(size_t)b * CC + c];
                if (v != 0.0f) {
                    int s2 = atomicAdd(&ovrCnt[b], 1);
                    if (s2 < OVROW) { ovS[b * OVROW + s2] = s; ovV[b * OVROW + s2] = v; }
                }
            }
            __syncthreads();
        }
    }
}

// =======================================================================
// D3: loss — 32 blocks x 32 rows, 8 threads/row; last block final-reduces.
// =======================================================================
__global__ __launch_bounds__(256) void k_loss(
        const float* __restrict__ simc, const int* __restrict__ rt,
        const int* __restrict__ pcnt, const int* __restrict__ pkidx,
        const float* __restrict__ pval, const float* __restrict__ seP,
        const int* __restrict__ ovrCnt, const float* __restrict__ ovS,
        const float* __restrict__ ovV, const float* __restrict__ ovSe,
        float* __restrict__ partials, int* __restrict__ doneCtr,
        float* __restrict__ outp)
{
    __shared__ float red[256];
    __shared__ int isLast;
    const int bid = blockIdx.x, tid = threadIdx.x;
    int b = bid * 32 + (tid >> 3);         // row
    int sub = tid & 7;                     // 8 threads per row
    const float* __restrict__ srow = simc + (size_t)b * KMAX;

    // se: 32 per-tile partials, 4 per sub-thread (float4)
    f32x4 sev = *(const f32x4*)(seP + (size_t)b * 32 + sub * 4);
    float se = sev[0] + sev[1] + sev[2] + sev[3];
    int cnt = pcnt[b]; if (cnt > PLCAP) cnt = PLCAP;
    float sp = 0.0f, spe = 0.0f;
    for (int i = sub; i < cnt; i += 8) {
        float v = pval[b * PLCAP + i];
        sp += v;
        spe += v * expf(srow[pkidx[b * PLCAP + i]]);
    }
    int oc = ovrCnt[b]; if (oc > OVROW) oc = OVROW;
    for (int i = sub; i < oc; i += 8) {
        float v = ovV[b * OVROW + i];
        sp += v;
        spe += v * expf(ovS[b * OVROW + i]);
    }
    // width-8 butterfly: all 8 lanes get the sums
    #pragma unroll
    for (int o = 1; o < 8; o <<= 1) {
        se  += __shfl_xor(se, o, 8);
        sp  += __shfl_xor(sp, o, 8);
        spe += __shfl_xor(spe, o, 8);
    }
    se += ovSe[b];
    float sneg = se - spe;                 // sum (1-pm)*exp over valid
    float inv = EPS_F / sp;
    float lb = 0.0f;
    for (int i = sub; i < cnt; i += 8) {
        float s = srow[pkidx[b * PLCAP + i]];
        lb += inv * pval[b * PLCAP + i] * (s - logf(sneg + expf(s)));
    }
    for (int i = sub; i < oc; i += 8) {
        float s = ovS[b * OVROW + i];
        lb += inv * ovV[b * OVROW + i] * (s - logf(sneg + expf(s)));
    }
    if (sub == 0) {
        float st = srow[rt[b]];
        lb += (1.0f - EPS_F) * (st - logf(sneg + expf(st)));
    }
    #pragma unroll
    for (int o = 1; o < 8; o <<= 1) lb += __shfl_xor(lb, o, 8);
    if (sub == 0) partials[b] = lb;
    __syncthreads();
    if (tid == 0) {
        __threadfence();
        isLast = (atomicAdd(doneCtr, 1) == 31);
    }
    __syncthreads();
    if (!isLast) return;
    __threadfence();                       // acquire partials from other XCDs
    float a = 0.0f;
    for (int i = tid; i < BB; i += 256) a += partials[i];
    red[tid] = a;
    __syncthreads();
    for (int s = 128; s > 0; s >>= 1) {
        if (tid < s) red[tid] += red[tid + s];
        __syncthreads();
    }
    if (tid == 0) outp[0] = -red[0] * (1.0f / BB);
}

extern "C" void kernel_launch(void* const* d_in, const int* in_sizes, int n_in,
                              void* d_out, int out_size, void* d_ws, size_t ws_size,
                              hipStream_t stream) {
    const float* inputs  = (const float*)d_in[0];
    const float* pmask   = (const float*)d_in[1];
    const float* fmem    = (const float*)d_in[2];
    const int*   lmem    = (const int*)d_in[3];
    const int*   targets = (const int*)d_in[4];
    float* outp = (float*)d_out;

    char* ws = (char*)d_ws;
    size_t off = 0;
    auto alloc = [&](size_t bytes) -> void* {
        void* p = ws + off;
        off = (off + bytes + 255) & ~(size_t)255;
        return p;
    };
    // zero region (single memset): ovcnt | doneCtr | ovrCnt | ovSe | pcnt |
    //                              gkey | gval   (key 0 = empty slot)
    const size_t ZINTS = 64 + 3 * BB + 2 * HSZ;
    int*    zreg    = (int*)alloc(ZINTS * sizeof(int));
    int*    ovcnt   = zreg;
    int*    doneCtr = zreg + 8;
    int*    ovrCnt  = zreg + 64;
    float*  ovSe    = (float*)(zreg + 64 + BB);
    int*    pcnt    = zreg + 64 + 2 * BB;
    int*    gkey    = zreg + 64 + 3 * BB;
    int*    gval    = gkey + HSZ;

    int*    rt      = (int*)alloc(BB * sizeof(int));
    int*    afirst  = (int*)alloc(BB * sizeof(int));
    int*    ovc     = (int*)alloc(OVCAP * sizeof(int));
    int*    pkidx   = (int*)alloc((size_t)BB * PLCAP * sizeof(int));
    float*  pval    = (float*)alloc((size_t)BB * PLCAP * sizeof(float));
    float*  ovS     = (float*)alloc((size_t)BB * OVROW * sizeof(float));
    float*  ovV     = (float*)alloc((size_t)BB * OVROW * sizeof(float));
    float*  rnA     = (float*)alloc(BB * sizeof(float));
    float*  rnB     = (float*)alloc(KMAX * sizeof(float));
    float*  seP     = (float*)alloc((size_t)BB * 32 * sizeof(float));
    float*  partials= (float*)alloc(BB * sizeof(float));
    bf16_t* AH      = (bf16_t*)alloc((size_t)BB * DD * sizeof(bf16_t));
    bf16_t* AL      = (bf16_t*)alloc((size_t)BB * DD * sizeof(bf16_t));
    bf16_t* BH      = (bf16_t*)alloc((size_t)KMAX * DD * sizeof(bf16_t));
    bf16_t* BL      = (bf16_t*)alloc((size_t)KMAX * DD * sizeof(bf16_t));
    float*  simc    = (float*)alloc((size_t)BB * KMAX * sizeof(float));

    hipMemsetAsync(zreg, 0, ZINTS * sizeof(int), stream);

    const int NLM = (CC + 255) / 256;                    // 196 lmem blocks
    k_setup<<<2 * BB + NLM, 256, 0, stream>>>(inputs, fmem, targets, lmem,
                                              AH, AL, BH, BL, rnA, rnB,
                                              rt, afirst, gkey, gval, ovc, ovcnt);
    k_main<<<3 * BB + OVCAP, 256, 0, stream>>>(pmask, targets, afirst,
                                               gkey, gval,
                                               AH, AL, BH, BL, rnA, rnB,
                                               simc, seP, pcnt, pkidx, pval,
                                               inputs, fmem, ovc, ovcnt,
                                               ovrCnt, ovS, ovV, ovSe);
    k_loss<<<32, 256, 0, stream>>>(simc, rt, pcnt, pkidx, pval, seP,
                                   ovrCnt, ovS, ovV, ovSe,
                                   partials, doneCtr, outp);
}

// Round 16
// 97.442 us; speedup vs baseline: 1.0074x; 1.0074x over previous
//
#include <hip/hip_runtime.h>
#include <math.h>

#define BB 1024        // batch
#define DD 512         // feature dim
#define CC 50000       // classes
#define KMAX 1024      // column space = batch rows (first-occurrence active)
#define HSZ 2048       // class->first-column hash size
#define PLCAP 32       // per-row positive-list capacity (expected ~2-6)
#define OVCAP 64       // overflow (lmem-valid unseen) class capacity
#define OVROW 8        // per-row overflow positive capacity
#define SCALE_F 16.0f
#define EPS_F 0.1f

typedef __bf16 bf16_t;
typedef bf16_t bf16x2 __attribute__((ext_vector_type(2)));
typedef bf16_t bf16x8 __attribute__((ext_vector_type(8)));
typedef float f32x4 __attribute__((ext_vector_type(4)));

__device__ __forceinline__ unsigned hashc(int c) {
    return ((unsigned)c * 2654435761u) >> 21;   // 0..2047
}

// =======================================================================
// D1: setup — row splits + rt, column (first-occurrence) class splits +
//     class->first-column hash insert, lmem overflow scan.
// =======================================================================
__global__ __launch_bounds__(256, 4) void k_setup(
        const float* __restrict__ inputs, const float* __restrict__ fmem,
        const int* __restrict__ targets, const int* __restrict__ lmem,
        bf16_t* __restrict__ AH, bf16_t* __restrict__ AL,
        bf16_t* __restrict__ BH, bf16_t* __restrict__ BL,
        float* __restrict__ rnA, float* __restrict__ rnB,
        int* __restrict__ rt, int* __restrict__ afirst,
        int* __restrict__ gkey, int* __restrict__ gval,
        int* __restrict__ ovc, int* __restrict__ ovcnt)
{
    __shared__ int tl[BB];
    __shared__ int members[BB];
    __shared__ float red[256];
    __shared__ int mc;
    const int bid = blockIdx.x, tid = threadIdx.x;

    for (int i = tid; i < BB; i += 256) tl[i] = targets[i];
    __syncthreads();

    if (bid < BB) {
        // ---- row path: rt[b] (first index of own target) + split + rnA ----
        int b = bid, tgt = tl[b];
        int lmin = 0x7fffffff;
        for (int j = tid; j < BB; j += 256)
            if (tl[j] == tgt && j < lmin) lmin = j;
        members[tid] = lmin;
        __syncthreads();
        for (int s = 128; s > 0; s >>= 1) {
            if (tid < s) members[tid] = min(members[tid], members[tid + s]);
            __syncthreads();
        }
        if (tid == 0) rt[b] = members[0];
        int d0 = tid * 2;
        float a0 = inputs[b * DD + d0];
        float a1 = inputs[b * DD + d0 + 1];
        red[tid] = a0 * a0 + a1 * a1;
        __syncthreads();
        for (int s = 128; s > 0; s >>= 1) {
            if (tid < s) red[tid] += red[tid + s];
            __syncthreads();
        }
        if (tid == 0) rnA[b] = 1.0f / fmaxf(sqrtf(red[0]), 1e-12f);
        bf16_t h0 = (bf16_t)a0, h1 = (bf16_t)a1;
        bf16x2 ph; ph[0] = h0; ph[1] = h1;
        bf16x2 pl; pl[0] = (bf16_t)(a0 - (float)h0); pl[1] = (bf16_t)(a1 - (float)h1);
        *(bf16x2*)(AH + b * DD + d0) = ph;
        *(bf16x2*)(AL + b * DD + d0) = pl;
    } else if (bid < 2 * BB) {
        // ---- column path: first-occurrence? class-mean split + rnB + hash --
        int j = bid - BB, tgt = tl[j];
        if (tid == 0) mc = 0;
        __syncthreads();
        int lmin = 0x7fffffff;
        for (int i = tid; i < BB; i += 256)
            if (tl[i] == tgt) { int s = atomicAdd(&mc, 1); members[s] = i; if (i < lmin) lmin = i; }
        red[tid] = (float)lmin;
        __syncthreads();
        for (int s = 128; s > 0; s >>= 1) {
            if (tid < s) red[tid] = fminf(red[tid], red[tid + s]);
            __syncthreads();
        }
        bool first = ((int)red[0] == j);
        int d0 = tid * 2;
        if (!first) {                       // duplicate class: dead column
            bf16x2 z; z[0] = (bf16_t)0.0f; z[1] = (bf16_t)0.0f;
            *(bf16x2*)(BH + j * DD + d0) = z;
            *(bf16x2*)(BL + j * DD + d0) = z;
            if (tid == 0) { rnB[j] = 0.0f; afirst[j] = 0; }
            return;
        }
        if (tid == 0) {                     // insert (class -> first column)
            unsigned h = hashc(tgt);
            while (true) {
                int old = atomicCAS(&gkey[h], 0, tgt + 1);
                if (old == 0) { gval[h] = j; break; }
                if (old == tgt + 1) break;  // impossible (unique first)
                h = (h + 1) & (HSZ - 1);
            }
        }
        int m = mc;
        float b0v = 0.0f, b1v = 0.0f;       // sum members; /count cancels
        for (int i = 0; i < m; ++i) {
            int bb = members[i];
            b0v += inputs[bb * DD + d0];
            b1v += inputs[bb * DD + d0 + 1];
        }
        __syncthreads();
        red[tid] = b0v * b0v + b1v * b1v;
        __syncthreads();
        for (int s = 128; s > 0; s >>= 1) {
            if (tid < s) red[tid] += red[tid + s];
            __syncthreads();
        }
        if (tid == 0) { rnB[j] = 1.0f / fmaxf(sqrtf(red[0]), 1e-12f); afirst[j] = 1; }
        bf16_t g0 = (bf16_t)b0v, g1 = (bf16_t)b1v;
        bf16x2 ph; ph[0] = g0; ph[1] = g1;
        bf16x2 pl; pl[0] = (bf16_t)(b0v - (float)g0); pl[1] = (bf16_t)(b1v - (float)g1);
        *(bf16x2*)(BH + j * DD + d0) = ph;
        *(bf16x2*)(BL + j * DD + d0) = pl;
    } else {
        // ---- lmem overflow scan (lmem is all -1 in this workload) ----
        int c = (bid - 2 * BB) * 256 + tid;
        if (c < CC && lmem[c] != -1) {
            bool seen = false;
            for (int i = 0; i < BB; ++i) if (tl[i] == c) { seen = true; break; }
            if (!seen) { int s = atomicAdd(ovcnt, 1); if (s < OVCAP) ovc[s] = c; }
        }
    }
}

// test one f32x4 against the class hash; append positives.
__device__ __forceinline__ void scan_test(f32x4 v, int cbase4, int b,
        const int* __restrict__ gkey, const int* __restrict__ gval,
        int* __restrict__ pcnt, int* __restrict__ pkidx, float* __restrict__ pval)
{
    if (v[0] == 0.0f && v[1] == 0.0f && v[2] == 0.0f && v[3] == 0.0f) return;
    #pragma unroll
    for (int j = 0; j < 4; ++j) {
        if (v[j] != 0.0f) {
            int c = cbase4 + j;
            unsigned h = hashc(c);
            while (true) {
                int k = gkey[h];                    // L2-hot 8KB table
                if (k == c + 1) {
                    int col = gval[h];              // first-occurrence column
                    int s = atomicAdd(&pcnt[b], 1);
                    if (s < PLCAP) {
                        pkidx[b * PLCAP + s] = col;
                        pval[b * PLCAP + s] = v[j];
                    }
                    break;
                }
                if (k == 0) break;                  // not a target class
                h = (h + 1) & (HSZ - 1);
            }
        }
    }
}

// =======================================================================
// D2: coalesced pm stream-scan with BATCHED loads (4 independent f32x4 in
//     flight per thread) ∥ 1024 MFMA tiles ∥ overflow blocks.
// =======================================================================
__global__ __launch_bounds__(256, 8) void k_main(
        const float* __restrict__ pm, const int* __restrict__ targets,
        const int* __restrict__ afirst,
        const int* __restrict__ gkey, const int* __restrict__ gval,
        const bf16_t* __restrict__ AH, const bf16_t* __restrict__ AL,
        const bf16_t* __restrict__ BH, const bf16_t* __restrict__ BL,
        const float* __restrict__ rnA, const float* __restrict__ rnB,
        float* __restrict__ simc, float* __restrict__ seP,
        int* __restrict__ pcnt, int* __restrict__ pkidx, float* __restrict__ pval,
        const float* __restrict__ inputs, const float* __restrict__ fmem,
        const int* __restrict__ ovc, const int* __restrict__ ovcnt,
        int* __restrict__ ovrCnt, float* __restrict__ ovS, float* __restrict__ ovV,
        float* __restrict__ ovSe)
{
    __shared__ float red[256];
    const int bid = blockIdx.x, tid = threadIdx.x;

    if (bid < 2 * BB) {
        // ---- stream-scan: half a pm row; 6 rounds x 4 batched loads + tail
        int b = bid >> 1, half = bid & 1;
        const int HQ = CC / 8;              // 6250 f32x4 per half-row
        const f32x4* __restrict__ rowv = (const f32x4*)(pm + (size_t)b * CC) + half * HQ;
        int cbase = half * (CC / 2);
        for (int r = 0; r < 6; ++r) {       // 6*1024 = 6144 f32x4
            int i0 = tid + r * 1024;
            f32x4 v0 = rowv[i0];            // 4 independent loads in flight
            f32x4 v1 = rowv[i0 + 256];
            f32x4 v2 = rowv[i0 + 512];
            f32x4 v3 = rowv[i0 + 768];
            scan_test(v0, cbase + (i0)       * 4, b, gkey, gval, pcnt, pkidx, pval);
            scan_test(v1, cbase + (i0 + 256) * 4, b, gkey, gval, pcnt, pkidx, pval);
            scan_test(v2, cbase + (i0 + 512) * 4, b, gkey, gval, pcnt, pkidx, pval);
            scan_test(v3, cbase + (i0 + 768) * 4, b, gkey, gval, pcnt, pkidx, pval);
        }
        if (tid < HQ - 6144) {              // tail: 106 f32x4
            int i0 = 6144 + tid;
            f32x4 v = rowv[i0];
            scan_test(v, cbase + i0 * 4, b, gkey, gval, pcnt, pkidx, pval);
        }
    } else if (bid < 3 * BB) {
        // ---- GEMM tile: 4 waves x one 16x16 quadrant, bf16 3-term split ----
        int t = bid - 2 * BB;
        float* sem = red;                  // 32 per-row exp partials
        if (tid < 32) sem[tid] = 0.0f;
        __syncthreads();
        int wave = tid >> 6, lane = tid & 63;
        int by = t >> 5, bx = t & 31;
        int b0 = by * 32 + (wave >> 1) * 16;
        int k0 = bx * 32 + (wave & 1) * 16;
        int frow = lane & 15;
        int koff = (lane >> 4) * 8;
        const bf16_t* pAh = AH + (size_t)(b0 + frow) * DD + koff;
        const bf16_t* pAl = AL + (size_t)(b0 + frow) * DD + koff;
        const bf16_t* pBh = BH + (size_t)(k0 + frow) * DD + koff;
        const bf16_t* pBl = BL + (size_t)(k0 + frow) * DD + koff;
        f32x4 acc = {};
        #pragma unroll 2
        for (int dk = 0; dk < DD; dk += 32) {
            bf16x8 ah = *(const bf16x8*)(pAh + dk);
            bf16x8 al = *(const bf16x8*)(pAl + dk);
            bf16x8 bh = *(const bf16x8*)(pBh + dk);
            bf16x8 bl = *(const bf16x8*)(pBl + dk);
            acc = __builtin_amdgcn_mfma_f32_16x16x32_bf16(ah, bh, acc, 0, 0, 0);
            acc = __builtin_amdgcn_mfma_f32_16x16x32_bf16(ah, bl, acc, 0, 0, 0);
            acc = __builtin_amdgcn_mfma_f32_16x16x32_bf16(al, bh, acc, 0, 0, 0);
        }
        // C/D layout: col = lane&15, row = (lane>>4)*4 + reg
        int r4 = (lane >> 4) * 4;
        int col = k0 + (lane & 15);
        float rb = rnB[col];
        int act = afirst[col];
        #pragma unroll
        for (int r = 0; r < 4; ++r) {
            int row = b0 + r4 + r;
            float s = acc[r] * SCALE_F * rnA[row] * rb;
            simc[(size_t)row * KMAX + col] = s;
            float e = act ? expf(s) : 0.0f;
            #pragma unroll
            for (int o = 1; o < 16; o <<= 1) e += __shfl_xor(e, o, 16);
            if ((lane & 15) == 0) atomicAdd(&sem[(wave >> 1) * 16 + r4 + r], e);
        }
        __syncthreads();
        if (tid < 32) seP[(size_t)(by * 32 + tid) * 32 + bx] = sem[tid];  // plain store
    } else {
        // ---- overflow classes (lmem-valid, unseen): generality path ----
        int i = bid - 3 * BB;
        int n = *ovcnt; if (n > OVCAP) n = OVCAP;
        if (i >= n) return;
        int c = ovc[i];
        float nn = 0.0f;
        for (int d = tid; d < DD; d += 256) { float x = fmem[(size_t)c * DD + d]; nn += x * x; }
        red[tid] = nn;
        __syncthreads();
        for (int s = 128; s > 0; s >>= 1) {
            if (tid < s) red[tid] += red[tid + s];
            __syncthreads();
        }
        float rn = 1.0f / fmaxf(sqrtf(red[0]), 1e-12f);
        __syncthreads();
        for (int b = 0; b < BB; ++b) {
            float part = 0.0f;
            for (int d = tid; d < DD; d += 256)
                part += inputs[b * DD + d] * fmem[(size_t)c * DD + d];
            red[tid] = part;
            __syncthreads();
            for (int s = 128; s > 0; s >>= 1) {
                if (tid < s) red[tid] += red[tid + s];
                __syncthreads();
            }
            if (tid == 0) {
                float s = SCALE_F * rnA[b] * rn * red[0];
                atomicAdd(&ovSe[b], expf(s));
                float v = pm[(size_t)b * CC + c];
                if (v != 0.0f) {
                    int s2 = atomicAdd(&ovrCnt[b], 1);
                    if (s2 < OVROW) { ovS[b * OVROW + s2] = s; ovV[b * OVROW + s2] = v; }
                }
            }
            __syncthreads();
        }
    }
}

// =======================================================================
// D3: loss — 32 blocks x 32 rows, 8 threads/row; last block final-reduces.
// =======================================================================
__global__ __launch_bounds__(256) void k_loss(
        const float* __restrict__ simc, const int* __restrict__ rt,
        const int* __restrict__ pcnt, const int* __restrict__ pkidx,
        const float* __restrict__ pval, const float* __restrict__ seP,
        const int* __restrict__ ovrCnt, const float* __restrict__ ovS,
        const float* __restrict__ ovV, const float* __restrict__ ovSe,
        float* __restrict__ partials, int* __restrict__ doneCtr,
        float* __restrict__ outp)
{
    __shared__ float red[256];
    __shared__ int isLast;
    const int bid = blockIdx.x, tid = threadIdx.x;
    int b = bid * 32 + (tid >> 3);         // row
    int sub = tid & 7;                     // 8 threads per row
    const float* __restrict__ srow = simc + (size_t)b * KMAX;

    // se: 32 per-tile partials, 4 per sub-thread (float4)
    f32x4 sev = *(const f32x4*)(seP + (size_t)b * 32 + sub * 4);
    float se = sev[0] + sev[1] + sev[2] + sev[3];
    int cnt = pcnt[b]; if (cnt > PLCAP) cnt = PLCAP;
    float sp = 0.0f, spe = 0.0f;
    for (int i = sub; i < cnt; i += 8) {
        float v = pval[b * PLCAP + i];
        sp += v;
        spe += v * expf(srow[pkidx[b * PLCAP + i]]);
    }
    int oc = ovrCnt[b]; if (oc > OVROW) oc = OVROW;
    for (int i = sub; i < oc; i += 8) {
        float v = ovV[b * OVROW + i];
        sp += v;
        spe += v * expf(ovS[b * OVROW + i]);
    }
    // width-8 butterfly: all 8 lanes get the sums
    #pragma unroll
    for (int o = 1; o < 8; o <<= 1) {
        se  += __shfl_xor(se, o, 8);
        sp  += __shfl_xor(sp, o, 8);
        spe += __shfl_xor(spe, o, 8);
    }
    se += ovSe[b];
    float sneg = se - spe;                 // sum (1-pm)*exp over valid
    float inv = EPS_F / sp;
    float lb = 0.0f;
    for (int i = sub; i < cnt; i += 8) {
        float s = srow[pkidx[b * PLCAP + i]];
        lb += inv * pval[b * PLCAP + i] * (s - logf(sneg + expf(s)));
    }
    for (int i = sub; i < oc; i += 8) {
        float s = ovS[b * OVROW + i];
        lb += inv * ovV[b * OVROW + i] * (s - logf(sneg + expf(s)));
    }
    if (sub == 0) {
        float st = srow[rt[b]];
        lb += (1.0f - EPS_F) * (st - logf(sneg + expf(st)));
    }
    #pragma unroll
    for (int o = 1; o < 8; o <<= 1) lb += __shfl_xor(lb, o, 8);
    if (sub == 0) partials[b] = lb;
    __syncthreads();
    if (tid == 0) {
        __threadfence();
        isLast = (atomicAdd(doneCtr, 1) == 31);
    }
    __syncthreads();
    if (!isLast) return;
    __threadfence();                       // acquire partials from other XCDs
    float a = 0.0f;
    for (int i = tid; i < BB; i += 256) a += partials[i];
    red[tid] = a;
    __syncthreads();
    for (int s = 128; s > 0; s >>= 1) {
        if (tid < s) red[tid] += red[tid + s];
        __syncthreads();
    }
    if (tid == 0) outp[0] = -red[0] * (1.0f / BB);
}

extern "C" void kernel_launch(void* const* d_in, const int* in_sizes, int n_in,
                              void* d_out, int out_size, void* d_ws, size_t ws_size,
                              hipStream_t stream) {
    const float* inputs  = (const float*)d_in[0];
    const float* pmask   = (const float*)d_in[1];
    const float* fmem    = (const float*)d_in[2];
    const int*   lmem    = (const int*)d_in[3];
    const int*   targets = (const int*)d_in[4];
    float* outp = (float*)d_out;

    char* ws = (char*)d_ws;
    size_t off = 0;
    auto alloc = [&](size_t bytes) -> void* {
        void* p = ws + off;
        off = (off + bytes + 255) & ~(size_t)255;
        return p;
    };
    // zero region (single memset): ovcnt | doneCtr | ovrCnt | ovSe | pcnt |
    //                              gkey | gval   (key 0 = empty slot)
    const size_t ZINTS = 64 + 3 * BB + 2 * HSZ;
    int*    zreg    = (int*)alloc(ZINTS * sizeof(int));
    int*    ovcnt   = zreg;
    int*    doneCtr = zreg + 8;
    int*    ovrCnt  = zreg + 64;
    float*  ovSe    = (float*)(zreg + 64 + BB);
    int*    pcnt    = zreg + 64 + 2 * BB;
    int*    gkey    = zreg + 64 + 3 * BB;
    int*    gval    = gkey + HSZ;

    int*    rt      = (int*)alloc(BB * sizeof(int));
    int*    afirst  = (int*)alloc(BB * sizeof(int));
    int*    ovc     = (int*)alloc(OVCAP * sizeof(int));
    int*    pkidx   = (int*)alloc((size_t)BB * PLCAP * sizeof(int));
    float*  pval    = (float*)alloc((size_t)BB * PLCAP * sizeof(float));
    float*  ovS     = (float*)alloc((size_t)BB * OVROW * sizeof(float));
    float*  ovV     = (float*)alloc((size_t)BB * OVROW * sizeof(float));
    float*  rnA     = (float*)alloc(BB * sizeof(float));
    float*  rnB     = (float*)alloc(KMAX * sizeof(float));
    float*  seP     = (float*)alloc((size_t)BB * 32 * sizeof(float));
    float*  partials= (float*)alloc(BB * sizeof(float));
    bf16_t* AH      = (bf16_t*)alloc((size_t)BB * DD * sizeof(bf16_t));
    bf16_t* AL      = (bf16_t*)alloc((size_t)BB * DD * sizeof(bf16_t));
    bf16_t* BH      = (bf16_t*)alloc((size_t)KMAX * DD * sizeof(bf16_t));
    bf16_t* BL      = (bf16_t*)alloc((size_t)KMAX * DD * sizeof(bf16_t));
    float*  simc    = (float*)alloc((size_t)BB * KMAX * sizeof(float));

    hipMemsetAsync(zreg, 0, ZINTS * sizeof(int), stream);

    const int NLM = (CC + 255) / 256;                    // 196 lmem blocks
    k_setup<<<2 * BB + NLM, 256, 0, stream>>>(inputs, fmem, targets, lmem,
                                              AH, AL, BH, BL, rnA, rnB,
                                              rt, afirst, gkey, gval, ovc, ovcnt);
    k_main<<<3 * BB + OVCAP, 256, 0, stream>>>(pmask, targets, afirst,
                                               gkey, gval,
                                               AH, AL, BH, BL, rnA, rnB,
                                               simc, seP, pcnt, pkidx, pval,
                                               inputs, fmem, ovc, ovcnt,
                                               ovrCnt, ovS, ovV, ovSe);
    k_loss<<<32, 256, 0, stream>>>(simc, rt, pcnt, pkidx, pval, seP,
                                   ovrCnt, ovS, ovV, ovSe,
                                   partials, doneCtr, outp);
}

// Round 17
// 68.479 us; speedup vs baseline: 1.4335x; 1.4230x over previous
//
#include <hip/hip_runtime.h>
#include <math.h>

#define BB 1024        // batch
#define DD 512         // feature dim
#define CC 50000       // classes
#define KMAX 1024      // column space = batch rows (first-occurrence active)
#define PLCAP 32       // per-row positive-list capacity (expected ~2-6)
#define OVCAP 64       // overflow (lmem-valid unseen) class capacity
#define OVROW 8        // per-row overflow positive capacity
#define SCALE_F 16.0f
#define EPS_F 0.1f

typedef __bf16 bf16_t;
typedef bf16_t bf16x2 __attribute__((ext_vector_type(2)));
typedef bf16_t bf16x8 __attribute__((ext_vector_type(8)));
typedef float f32x4 __attribute__((ext_vector_type(4)));

// =======================================================================
// D1: setup — row splits + rt, column (first-occurrence) class splits,
//     lmem overflow scan. All block-independent.
// =======================================================================
__global__ __launch_bounds__(256, 4) void k_setup(
        const float* __restrict__ inputs, const float* __restrict__ fmem,
        const int* __restrict__ targets, const int* __restrict__ lmem,
        bf16_t* __restrict__ AH, bf16_t* __restrict__ AL,
        bf16_t* __restrict__ BH, bf16_t* __restrict__ BL,
        float* __restrict__ rnA, float* __restrict__ rnB,
        int* __restrict__ rt, int* __restrict__ afirst,
        int* __restrict__ ovc, int* __restrict__ ovcnt)
{
    __shared__ int tl[BB];
    __shared__ int members[BB];
    __shared__ float red[256];
    __shared__ int mc;
    const int bid = blockIdx.x, tid = threadIdx.x;

    for (int i = tid; i < BB; i += 256) tl[i] = targets[i];
    __syncthreads();

    if (bid < BB) {
        // ---- row path: rt[b] (first index of own target) + split + rnA ----
        int b = bid, tgt = tl[b];
        int lmin = 0x7fffffff;
        for (int j = tid; j < BB; j += 256)
            if (tl[j] == tgt && j < lmin) lmin = j;
        members[tid] = lmin;
        __syncthreads();
        for (int s = 128; s > 0; s >>= 1) {
            if (tid < s) members[tid] = min(members[tid], members[tid + s]);
            __syncthreads();
        }
        if (tid == 0) rt[b] = members[0];
        int d0 = tid * 2;
        float a0 = inputs[b * DD + d0];
        float a1 = inputs[b * DD + d0 + 1];
        red[tid] = a0 * a0 + a1 * a1;
        __syncthreads();
        for (int s = 128; s > 0; s >>= 1) {
            if (tid < s) red[tid] += red[tid + s];
            __syncthreads();
        }
        if (tid == 0) rnA[b] = 1.0f / fmaxf(sqrtf(red[0]), 1e-12f);
        bf16_t h0 = (bf16_t)a0, h1 = (bf16_t)a1;
        bf16x2 ph; ph[0] = h0; ph[1] = h1;
        bf16x2 pl; pl[0] = (bf16_t)(a0 - (float)h0); pl[1] = (bf16_t)(a1 - (float)h1);
        *(bf16x2*)(AH + b * DD + d0) = ph;
        *(bf16x2*)(AL + b * DD + d0) = pl;
    } else if (bid < 2 * BB) {
        // ---- column path: first-occurrence? class-mean split + rnB ----
        int j = bid - BB, tgt = tl[j];
        if (tid == 0) mc = 0;
        __syncthreads();
        int lmin = 0x7fffffff;
        for (int i = tid; i < BB; i += 256)
            if (tl[i] == tgt) { int s = atomicAdd(&mc, 1); members[s] = i; if (i < lmin) lmin = i; }
        red[tid] = (float)lmin;
        __syncthreads();
        for (int s = 128; s > 0; s >>= 1) {
            if (tid < s) red[tid] = fminf(red[tid], red[tid + s]);
            __syncthreads();
        }
        bool first = ((int)red[0] == j);
        int d0 = tid * 2;
        if (!first) {                       // duplicate class: dead column
            bf16x2 z; z[0] = (bf16_t)0.0f; z[1] = (bf16_t)0.0f;
            *(bf16x2*)(BH + j * DD + d0) = z;
            *(bf16x2*)(BL + j * DD + d0) = z;
            if (tid == 0) { rnB[j] = 0.0f; afirst[j] = 0; }
            return;
        }
        int m = mc;
        float b0v = 0.0f, b1v = 0.0f;       // sum members; /count cancels
        for (int i = 0; i < m; ++i) {
            int bb = members[i];
            b0v += inputs[bb * DD + d0];
            b1v += inputs[bb * DD + d0 + 1];
        }
        __syncthreads();
        red[tid] = b0v * b0v + b1v * b1v;
        __syncthreads();
        for (int s = 128; s > 0; s >>= 1) {
            if (tid < s) red[tid] += red[tid + s];
            __syncthreads();
        }
        if (tid == 0) { rnB[j] = 1.0f / fmaxf(sqrtf(red[0]), 1e-12f); afirst[j] = 1; }
        bf16_t g0 = (bf16_t)b0v, g1 = (bf16_t)b1v;
        bf16x2 ph; ph[0] = g0; ph[1] = g1;
        bf16x2 pl; pl[0] = (bf16_t)(b0v - (float)g0); pl[1] = (bf16_t)(b1v - (float)g1);
        *(bf16x2*)(BH + j * DD + d0) = ph;
        *(bf16x2*)(BL + j * DD + d0) = pl;
    } else {
        // ---- lmem overflow scan (lmem is all -1 in this workload) ----
        int c = (bid - 2 * BB) * 256 + tid;
        if (c < CC && lmem[c] != -1) {
            bool seen = false;
            for (int i = 0; i < BB; ++i) if (tl[i] == c) { seen = true; break; }
            if (!seen) { int s = atomicAdd(ovcnt, 1); if (s < OVCAP) ovc[s] = c; }
        }
    }
}

// =======================================================================
// D2: gather (full width, max MLP) ∥ 1024 MFMA tiles ∥ overflow.
// =======================================================================
__global__ __launch_bounds__(256, 8) void k_main(
        const float* __restrict__ pm, const int* __restrict__ targets,
        const int* __restrict__ afirst,
        const bf16_t* __restrict__ AH, const bf16_t* __restrict__ AL,
        const bf16_t* __restrict__ BH, const bf16_t* __restrict__ BL,
        const float* __restrict__ rnA, const float* __restrict__ rnB,
        float* __restrict__ simc, float* __restrict__ seP,
        int* __restrict__ pcnt, int* __restrict__ pkidx, float* __restrict__ pval,
        const float* __restrict__ inputs, const float* __restrict__ fmem,
        const int* __restrict__ ovc, const int* __restrict__ ovcnt,
        int* __restrict__ ovrCnt, float* __restrict__ ovS, float* __restrict__ ovV,
        float* __restrict__ ovSe)
{
    __shared__ int tl[BB];
    __shared__ int af[BB];
    __shared__ float red[256];
    __shared__ int mc;
    __shared__ int lk[PLCAP];
    __shared__ float lv[PLCAP];
    const int bid = blockIdx.x, tid = threadIdx.x;

    if (bid < BB) {
        // ---- gather row b: stage 4 independent loads, then test/append ----
        for (int i = tid; i < BB; i += 256) { tl[i] = targets[i]; af[i] = afirst[i]; }
        if (tid == 0) mc = 0;
        __syncthreads();
        int b = bid;
        const float* __restrict__ row = pm + (size_t)b * CC;
        float v0 = row[tl[tid]];
        float v1 = row[tl[tid + 256]];
        float v2 = row[tl[tid + 512]];
        float v3 = row[tl[tid + 768]];
        if (af[tid] && v0 != 0.0f)       { int s = atomicAdd(&mc, 1); if (s < PLCAP) { lk[s] = tid;       lv[s] = v0; } }
        if (af[tid + 256] && v1 != 0.0f) { int s = atomicAdd(&mc, 1); if (s < PLCAP) { lk[s] = tid + 256; lv[s] = v1; } }
        if (af[tid + 512] && v2 != 0.0f) { int s = atomicAdd(&mc, 1); if (s < PLCAP) { lk[s] = tid + 512; lv[s] = v2; } }
        if (af[tid + 768] && v3 != 0.0f) { int s = atomicAdd(&mc, 1); if (s < PLCAP) { lk[s] = tid + 768; lv[s] = v3; } }
        __syncthreads();
        int n = mc < PLCAP ? mc : PLCAP;
        if (tid == 0) pcnt[b] = n;
        if (tid < n) { pkidx[b * PLCAP + tid] = lk[tid]; pval[b * PLCAP + tid] = lv[tid]; }
    } else if (bid < 2 * BB) {
        // ---- GEMM tile: 4 waves x one 16x16 quadrant, bf16 3-term split ----
        int t = bid - BB;
        float* sem = red;                  // 32 per-row exp partials
        if (tid < 32) sem[tid] = 0.0f;
        __syncthreads();
        int wave = tid >> 6, lane = tid & 63;
        int by = t >> 5, bx = t & 31;
        int b0 = by * 32 + (wave >> 1) * 16;
        int k0 = bx * 32 + (wave & 1) * 16;
        int frow = lane & 15;
        int koff = (lane >> 4) * 8;
        const bf16_t* pAh = AH + (size_t)(b0 + frow) * DD + koff;
        const bf16_t* pAl = AL + (size_t)(b0 + frow) * DD + koff;
        const bf16_t* pBh = BH + (size_t)(k0 + frow) * DD + koff;
        const bf16_t* pBl = BL + (size_t)(k0 + frow) * DD + koff;
        f32x4 acc = {};
        #pragma unroll 2
        for (int dk = 0; dk < DD; dk += 32) {
            bf16x8 ah = *(const bf16x8*)(pAh + dk);
            bf16x8 al = *(const bf16x8*)(pAl + dk);
            bf16x8 bh = *(const bf16x8*)(pBh + dk);
            bf16x8 bl = *(const bf16x8*)(pBl + dk);
            acc = __builtin_amdgcn_mfma_f32_16x16x32_bf16(ah, bh, acc, 0, 0, 0);
            acc = __builtin_amdgcn_mfma_f32_16x16x32_bf16(ah, bl, acc, 0, 0, 0);
            acc = __builtin_amdgcn_mfma_f32_16x16x32_bf16(al, bh, acc, 0, 0, 0);
        }
        // C/D layout: col = lane&15, row = (lane>>4)*4 + reg
        int r4 = (lane >> 4) * 4;
        int col = k0 + (lane & 15);
        float rb = rnB[col];
        int act = afirst[col];
        #pragma unroll
        for (int r = 0; r < 4; ++r) {
            int row = b0 + r4 + r;
            float s = acc[r] * SCALE_F * rnA[row] * rb;
            simc[(size_t)row * KMAX + col] = s;
            float e = act ? expf(s) : 0.0f;
            #pragma unroll
            for (int o = 1; o < 16; o <<= 1) e += __shfl_xor(e, o, 16);
            if ((lane & 15) == 0) atomicAdd(&sem[(wave >> 1) * 16 + r4 + r], e);
        }
        __syncthreads();
        if (tid < 32) seP[(size_t)(by * 32 + tid) * 32 + bx] = sem[tid];  // plain store
    } else {
        // ---- overflow classes (lmem-valid, unseen): generality path ----
        int i = bid - 2 * BB;
        int n = *ovcnt; if (n > OVCAP) n = OVCAP;
        if (i >= n) return;
        int c = ovc[i];
        float nn = 0.0f;
        for (int d = tid; d < DD; d += 256) { float x = fmem[(size_t)c * DD + d]; nn += x * x; }
        red[tid] = nn;
        __syncthreads();
        for (int s = 128; s > 0; s >>= 1) {
            if (tid < s) red[tid] += red[tid + s];
            __syncthreads();
        }
        float rn = 1.0f / fmaxf(sqrtf(red[0]), 1e-12f);
        __syncthreads();
        for (int b = 0; b < BB; ++b) {
            float part = 0.0f;
            for (int d = tid; d < DD; d += 256)
                part += inputs[b * DD + d] * fmem[(size_t)c * DD + d];
            red[tid] = part;
            __syncthreads();
            for (int s = 128; s > 0; s >>= 1) {
                if (tid < s) red[tid] += red[tid + s];
                __syncthreads();
            }
            if (tid == 0) {
                float s = SCALE_F * rnA[b] * rn * red[0];
                atomicAdd(&ovSe[b], expf(s));
                float v = pm[(size_t)b * CC + c];
                if (v != 0.0f) {
                    int s2 = atomicAdd(&ovrCnt[b], 1);
                    if (s2 < OVROW) { ovS[b * OVROW + s2] = s; ovV[b * OVROW + s2] = v; }
                }
            }
            __syncthreads();
        }
    }
}

// =======================================================================
// D3: loss — 32 blocks x 32 rows, 8 threads/row; last block final-reduces.
// =======================================================================
__global__ __launch_bounds__(256) void k_loss(
        const float* __restrict__ simc, const int* __restrict__ rt,
        const int* __restrict__ pcnt, const int* __restrict__ pkidx,
        const float* __restrict__ pval, const float* __restrict__ seP,
        const int* __restrict__ ovrCnt, const float* __restrict__ ovS,
        const float* __restrict__ ovV, const float* __restrict__ ovSe,
        float* __restrict__ partials, int* __restrict__ doneCtr,
        float* __restrict__ outp)
{
    __shared__ float red[256];
    __shared__ int isLast;
    const int bid = blockIdx.x, tid = threadIdx.x;
    int b = bid * 32 + (tid >> 3);         // row
    int sub = tid & 7;                     // 8 threads per row
    const float* __restrict__ srow = simc + (size_t)b * KMAX;

    // se: 32 per-tile partials, 4 per sub-thread (float4)
    f32x4 sev = *(const f32x4*)(seP + (size_t)b * 32 + sub * 4);
    float se = sev[0] + sev[1] + sev[2] + sev[3];
    int cnt = pcnt[b]; if (cnt > PLCAP) cnt = PLCAP;
    float sp = 0.0f, spe = 0.0f;
    for (int i = sub; i < cnt; i += 8) {
        float v = pval[b * PLCAP + i];
        sp += v;
        spe += v * expf(srow[pkidx[b * PLCAP + i]]);
    }
    int oc = ovrCnt[b]; if (oc > OVROW) oc = OVROW;
    for (int i = sub; i < oc; i += 8) {
        float v = ovV[b * OVROW + i];
        sp += v;
        spe += v * expf(ovS[b * OVROW + i]);
    }
    // width-8 butterfly: all 8 lanes get the sums
    #pragma unroll
    for (int o = 1; o < 8; o <<= 1) {
        se  += __shfl_xor(se, o, 8);
        sp  += __shfl_xor(sp, o, 8);
        spe += __shfl_xor(spe, o, 8);
    }
    se += ovSe[b];
    float sneg = se - spe;                 // sum (1-pm)*exp over valid
    float inv = EPS_F / sp;
    float lb = 0.0f;
    for (int i = sub; i < cnt; i += 8) {
        float s = srow[pkidx[b * PLCAP + i]];
        lb += inv * pval[b * PLCAP + i] * (s - logf(sneg + expf(s)));
    }
    for (int i = sub; i < oc; i += 8) {
        float s = ovS[b * OVROW + i];
        lb += inv * ovV[b * OVROW + i] * (s - logf(sneg + expf(s)));
    }
    if (sub == 0) {
        float st = srow[rt[b]];
        lb += (1.0f - EPS_F) * (st - logf(sneg + expf(st)));
    }
    #pragma unroll
    for (int o = 1; o < 8; o <<= 1) lb += __shfl_xor(lb, o, 8);
    if (sub == 0) partials[b] = lb;
    __syncthreads();
    if (tid == 0) {
        __threadfence();
        isLast = (atomicAdd(doneCtr, 1) == 31);
    }
    __syncthreads();
    if (!isLast) return;
    __threadfence();                       // acquire partials from other XCDs
    float a = 0.0f;
    for (int i = tid; i < BB; i += 256) a += partials[i];
    red[tid] = a;
    __syncthreads();
    for (int s = 128; s > 0; s >>= 1) {
        if (tid < s) red[tid] += red[tid + s];
        __syncthreads();
    }
    if (tid == 0) outp[0] = -red[0] * (1.0f / BB);
}

extern "C" void kernel_launch(void* const* d_in, const int* in_sizes, int n_in,
                              void* d_out, int out_size, void* d_ws, size_t ws_size,
                              hipStream_t stream) {
    const float* inputs  = (const float*)d_in[0];
    const float* pmask   = (const float*)d_in[1];
    const float* fmem    = (const float*)d_in[2];
    const int*   lmem    = (const int*)d_in[3];
    const int*   targets = (const int*)d_in[4];
    float* outp = (float*)d_out;

    char* ws = (char*)d_ws;
    size_t off = 0;
    auto alloc = [&](size_t bytes) -> void* {
        void* p = ws + off;
        off = (off + bytes + 255) & ~(size_t)255;
        return p;
    };
    // zero region (single small memset): ovcnt | doneCtr | ovrCnt | ovSe
    int*    zreg    = (int*)alloc(256 + 2 * BB * sizeof(int));
    int*    ovcnt   = zreg;
    int*    doneCtr = zreg + 8;
    int*    ovrCnt  = zreg + 64;
    float*  ovSe    = (float*)(zreg + 64 + BB);
    size_t  zbytes  = 256 + 2 * BB * sizeof(int);

    int*    rt      = (int*)alloc(BB * sizeof(int));
    int*    afirst  = (int*)alloc(BB * sizeof(int));
    int*    ovc     = (int*)alloc(OVCAP * sizeof(int));
    int*    pcnt    = (int*)alloc(BB * sizeof(int));
    int*    pkidx   = (int*)alloc((size_t)BB * PLCAP * sizeof(int));
    float*  pval    = (float*)alloc((size_t)BB * PLCAP * sizeof(float));
    float*  ovS     = (float*)alloc((size_t)BB * OVROW * sizeof(float));
    float*  ovV     = (float*)alloc((size_t)BB * OVROW * sizeof(float));
    float*  rnA     = (float*)alloc(BB * sizeof(float));
    float*  rnB     = (float*)alloc(KMAX * sizeof(float));
    float*  seP     = (float*)alloc((size_t)BB * 32 * sizeof(float));
    float*  partials= (float*)alloc(BB * sizeof(float));
    bf16_t* AH      = (bf16_t*)alloc((size_t)BB * DD * sizeof(bf16_t));
    bf16_t* AL      = (bf16_t*)alloc((size_t)BB * DD * sizeof(bf16_t));
    bf16_t* BH      = (bf16_t*)alloc((size_t)KMAX * DD * sizeof(bf16_t));
    bf16_t* BL      = (bf16_t*)alloc((size_t)KMAX * DD * sizeof(bf16_t));
    float*  simc    = (float*)alloc((size_t)BB * KMAX * sizeof(float));

    hipMemsetAsync(zreg, 0, zbytes, stream);

    const int NLM = (CC + 255) / 256;                    // 196 lmem blocks
    k_setup<<<2 * BB + NLM, 256, 0, stream>>>(inputs, fmem, targets, lmem,
                                              AH, AL, BH, BL, rnA, rnB,
                                              rt, afirst, ovc, ovcnt);
    k_main<<<2 * BB + OVCAP, 256, 0, stream>>>(pmask, targets, afirst,
                                               AH, AL, BH, BL, rnA, rnB,
                                               simc, seP, pcnt, pkidx, pval,
                                               inputs, fmem, ovc, ovcnt,
                                               ovrCnt, ovS, ovV, ovSe);
    k_loss<<<32, 256, 0, stream>>>(simc, rt, pcnt, pkidx, pval, seP,
                                   ovrCnt, ovS, ovV, ovSe,
                                   partials, doneCtr, outp);
}